// Round 1
// baseline (14183.620 us; speedup 1.0000x reference)
//
#include <hip/hip_runtime.h>
#include <math.h>

#define BB 128
#define SS 1024
#define MM 64
#define KDIM 128
#define VDIM 256
#define FDIM 128
#define QNUM 5000

__device__ __forceinline__ float sigmoidf_(float x) { return 1.0f / (1.0f + expf(-x)); }
__device__ __forceinline__ float softplusf_(float x) { return (x > 20.0f) ? x : log1pf(expf(x)); }

__global__ __launch_bounds__(256) void dkvmn_kernel(
    const int* __restrict__ q_data, const int* __restrict__ r_data,
    const float* __restrict__ q_embed, const float* __restrict__ key_mem,
    const float* __restrict__ init_mv,
    const float* __restrict__ W_value, const float* __restrict__ b_value,
    const float* __restrict__ W_erase, const float* __restrict__ b_erase,
    const float* __restrict__ W_add, const float* __restrict__ b_add,
    const float* __restrict__ W_summary, const float* __restrict__ b_summary,
    const float* __restrict__ W_theta, const float* __restrict__ b_theta,
    const float* __restrict__ W_beta, const float* __restrict__ b_beta,
    const float* __restrict__ W_disc, const float* __restrict__ b_disc,
    const float* __restrict__ W_c1, const float* __restrict__ b_c1,
    const float* __restrict__ W_c2, const float* __restrict__ b_c2,
    const float* __restrict__ coral_w, const float* __restrict__ coral_b,
    float* __restrict__ out)
{
  const int b   = blockIdx.x;
  const int tid = threadIdx.x;

  __shared__ float s_key[MM * KDIM];        // 32 KB
  __shared__ int   s_qt[SS];                // 4 KB
  __shared__ int   s_rt[SS];                // 4 KB
  __shared__ float s_x[VDIM + KDIM];        // [read(256) | qe(128)]
  __shared__ float s_ve[VDIM];
  __shared__ float s_logits[MM];
  __shared__ float s_w[MM];
  __shared__ float s_summary[FDIM];
  __shared__ float s_feat[8];
  __shared__ float s_h1[64];
  __shared__ float s_Wc1[5 * 64];
  __shared__ float s_bc1[64];
  __shared__ float s_Wc2[64 * 32];
  __shared__ float s_bc2[32];
  __shared__ float s_cw[32];

  // ---- one-time staging ----
  for (int i = tid; i < MM * KDIM; i += 256) s_key[i] = key_mem[i];
  for (int i = tid; i < SS; i += 256) {
    s_qt[i] = q_data[(size_t)b * SS + i];
    s_rt[i] = r_data[(size_t)b * SS + i];
  }
  for (int i = tid; i < 5 * 64; i += 256) s_Wc1[i] = W_c1[i];
  for (int i = tid; i < 64 * 32; i += 256) s_Wc2[i] = W_c2[i];
  if (tid < 64) s_bc1[tid] = b_c1[tid];
  if (tid < 32) { s_bc2[tid] = b_c2[tid]; s_cw[tid] = coral_w[tid]; }

  // Mv state: thread v owns Mv[m][v] for all m
  float mv[MM];
#pragma unroll
  for (int m = 0; m < MM; ++m) mv[m] = init_mv[m * VDIM + tid];

  // per-thread constant hoists
  const float bval   = b_value[tid];
  const float berase = b_erase[tid];
  const float badd   = b_add[tid];
  const int   f      = tid >> 1;         // summary output index (2 threads per f)
  const int   hh     = tid & 1;
  const float bsum   = hh ? 0.0f : b_summary[f];

  const int wave = tid >> 6, lane = tid & 63;
  float hw0 = 0.f, hw1 = 0.f, hw2 = 0.f, hw3 = 0.f, hw4 = 0.f, hw5 = 0.f;
  float hb0 = 0.f, hb1 = 0.f, hb2 = 0.f;
  if (wave == 0) {
    hw0 = W_theta[lane]; hw1 = W_theta[lane + 64]; hb0 = b_theta[0];
  } else if (wave == 1) {
    hw0 = W_disc[lane]; hw1 = W_disc[lane + 64];
    hw2 = W_disc[128 + lane]; hw3 = W_disc[192 + lane]; hb0 = b_disc[0];
  } else if (wave == 2) {
    hw0 = W_beta[lane * 3 + 0]; hw1 = W_beta[lane * 3 + 1]; hw2 = W_beta[lane * 3 + 2];
    hw3 = W_beta[(lane + 64) * 3 + 0]; hw4 = W_beta[(lane + 64) * 3 + 1]; hw5 = W_beta[(lane + 64) * 3 + 2];
    hb0 = b_beta[0]; hb1 = b_beta[1]; hb2 = b_beta[2];
  }
  float cb0 = 0.f, cb1 = 0.f, cb2 = 0.f;
  if (tid == 0) { cb0 = coral_b[0]; cb1 = coral_b[1]; cb2 = coral_b[2]; }

  float* out_theta = out;
  float* out_beta  = out + (size_t)BB * SS;
  float* out_alpha = out + (size_t)BB * SS * 4;
  float* out_probs = out + (size_t)BB * SS * 5;
  float* out_logit = out + (size_t)BB * SS * 9;

  __syncthreads();

  for (int t = 0; t < SS; ++t) {
    const int   qt    = s_qt[t];
    const float scale = (float)s_rt[t] * (1.0f / 3.0f);

    // qe -> s_x[256..383]
    if (tid < KDIM) s_x[VDIM + tid] = q_embed[(size_t)qt * KDIM + tid];
    // ve (ordered-embedding one-hot trick)
    float ve = bval;
    if (qt >= 1) {
      ve += W_value[(size_t)(qt - 1) * VDIM + tid]
          + scale * W_value[(size_t)(QNUM + qt - 1) * VDIM + tid];
    }
    s_ve[tid] = ve;
    __syncthreads();

    // ---- key logits: 4 threads per m, rotated LDS access (2-way conflict = free) ----
    {
      const int m = tid >> 2, j = tid & 3;
      const float* krow = s_key + m * KDIM + j * 32;
      const float* qrow = s_x + VDIM + j * 32;
      float acc = 0.f;
#pragma unroll
      for (int k = 0; k < 32; ++k) {
        const int i = (k + tid) & 31;
        acc += qrow[i] * krow[i];
      }
      acc += __shfl_xor(acc, 1);
      acc += __shfl_xor(acc, 2);
      if (j == 0) s_logits[m] = acc;
    }
    __syncthreads();

    // ---- softmax over 64 (wave 0) ----
    if (tid < 64) {
      const float x = s_logits[tid];
      float mx = x;
#pragma unroll
      for (int o = 32; o; o >>= 1) mx = fmaxf(mx, __shfl_xor(mx, o));
      const float e = expf(x - mx);
      float s = e;
#pragma unroll
      for (int o = 32; o; o >>= 1) s += __shfl_xor(s, o);
      s_w[tid] = e / s;
    }
    __syncthreads();

    // ---- read[v] = sum_m w[m]*Mv[m][v] (thread-local Mv) ----
    {
      float r0 = 0.f, r1 = 0.f;
#pragma unroll
      for (int m = 0; m < MM; m += 2) {
        r0 += s_w[m] * mv[m];
        r1 += s_w[m + 1] * mv[m + 1];
      }
      s_x[tid] = r0 + r1;
    }
    __syncthreads();

    // ---- summary: 2 threads per output f; x = [read | qe] (384) ----
    {
      const int i0 = hh * 192;
      float a0 = bsum, a1 = 0.f;
#pragma unroll 8
      for (int ii = 0; ii < 192; ii += 2) {
        a0 += s_x[i0 + ii]     * W_summary[(i0 + ii) * FDIM + f];
        a1 += s_x[i0 + ii + 1] * W_summary[(i0 + ii + 1) * FDIM + f];
      }
      float a = a0 + a1;
      a += __shfl_xor(a, 1);
      if (hh == 0) s_summary[f] = tanhf(a);
    }
    __syncthreads();

    // ---- scalar heads (per-wave) ----
    if (wave == 0) {
      float a = s_summary[lane] * hw0 + s_summary[lane + 64] * hw1;
#pragma unroll
      for (int o = 32; o; o >>= 1) a += __shfl_xor(a, o);
      if (lane == 0) s_feat[0] = (a + hb0) * 3.0f;   // theta (scaled)
    } else if (wave == 1) {
      float a = s_summary[lane] * hw0 + s_summary[lane + 64] * hw1
              + s_x[VDIM + lane] * hw2 + s_x[VDIM + lane + 64] * hw3;
#pragma unroll
      for (int o = 32; o; o >>= 1) a += __shfl_xor(a, o);
      if (lane == 0) s_feat[1] = softplusf_(a + hb0); // alpha
    } else if (wave == 2) {
      const float q0 = s_x[VDIM + lane], q1 = s_x[VDIM + lane + 64];
      float a0 = q0 * hw0 + q1 * hw3;
      float a1 = q0 * hw1 + q1 * hw4;
      float a2 = q0 * hw2 + q1 * hw5;
#pragma unroll
      for (int o = 32; o; o >>= 1) {
        a0 += __shfl_xor(a0, o); a1 += __shfl_xor(a1, o); a2 += __shfl_xor(a2, o);
      }
      if (lane == 0) { s_feat[2] = a0 + hb0; s_feat[3] = a1 + hb1; s_feat[4] = a2 + hb2; }
    }
    __syncthreads();

    // ---- CORAL MLP ----
    if (tid < 64) {
      float a = s_bc1[tid];
#pragma unroll
      for (int i = 0; i < 5; ++i) a += s_feat[i] * s_Wc1[i * 64 + tid];
      s_h1[tid] = fmaxf(a, 0.f);
    }
    __syncthreads();
    if (tid < 32) {
      float a = s_bc2[tid];
#pragma unroll 8
      for (int i = 0; i < 64; ++i) a += s_h1[i] * s_Wc2[i * 32 + tid];
      const float h2 = fmaxf(a, 0.f);
      float z = h2 * s_cw[tid];
#pragma unroll
      for (int o = 16; o; o >>= 1) z += __shfl_xor(z, o);
      if (tid == 0) {
        const float l0 = z + cb0, l1 = z + cb1, l2 = z + cb2;
        const float s0 = sigmoidf_(l0), s1 = sigmoidf_(l1), s2 = sigmoidf_(l2);
        const float c0 = s0, c1 = s0 * s1, c2 = s0 * s1 * s2;
        const size_t bt = (size_t)b * SS + t;
        out_theta[bt] = s_feat[0];
        out_alpha[bt] = s_feat[1];
        out_beta[bt * 3 + 0] = s_feat[2];
        out_beta[bt * 3 + 1] = s_feat[3];
        out_beta[bt * 3 + 2] = s_feat[4];
        out_logit[bt * 3 + 0] = l0;
        out_logit[bt * 3 + 1] = l1;
        out_logit[bt * 3 + 2] = l2;
        out_probs[bt * 4 + 0] = 1.f - c0;
        out_probs[bt * 4 + 1] = c0 - c1;
        out_probs[bt * 4 + 2] = c1 - c2;
        out_probs[bt * 4 + 3] = c2;
      }
    }

    // ---- erase / add (all 256 threads, output v = tid) ----
    {
      float e0 = berase, e1 = 0.f, a0 = badd, a1 = 0.f;
#pragma unroll 8
      for (int i = 0; i < VDIM; i += 2) {
        const float v0 = s_ve[i], v1 = s_ve[i + 1];
        e0 += v0 * W_erase[i * VDIM + tid];
        e1 += v1 * W_erase[(i + 1) * VDIM + tid];
        a0 += v0 * W_add[i * VDIM + tid];
        a1 += v1 * W_add[(i + 1) * VDIM + tid];
      }
      const float er = sigmoidf_(e0 + e1);
      const float ad = tanhf(a0 + a1);

      // Mv update (thread-local)
#pragma unroll
      for (int m = 0; m < MM; ++m) {
        const float wm = s_w[m];
        mv[m] = mv[m] * (1.0f - wm * er) + wm * ad;
      }
    }
    __syncthreads();  // protect LDS overwrite next step
  }
}

extern "C" void kernel_launch(void* const* d_in, const int* in_sizes, int n_in,
                              void* d_out, int out_size, void* d_ws, size_t ws_size,
                              hipStream_t stream) {
  const int*   q_data    = (const int*)d_in[0];
  const int*   r_data    = (const int*)d_in[1];
  const float* q_embed   = (const float*)d_in[2];
  const float* key_mem   = (const float*)d_in[3];
  const float* init_mv   = (const float*)d_in[4];
  const float* W_value   = (const float*)d_in[5];
  const float* b_value   = (const float*)d_in[6];
  const float* W_erase   = (const float*)d_in[7];
  const float* b_erase   = (const float*)d_in[8];
  const float* W_add     = (const float*)d_in[9];
  const float* b_add     = (const float*)d_in[10];
  const float* W_summary = (const float*)d_in[11];
  const float* b_summary = (const float*)d_in[12];
  const float* W_theta   = (const float*)d_in[13];
  const float* b_theta   = (const float*)d_in[14];
  const float* W_beta    = (const float*)d_in[15];
  const float* b_beta    = (const float*)d_in[16];
  const float* W_disc    = (const float*)d_in[17];
  const float* b_disc    = (const float*)d_in[18];
  const float* W_c1      = (const float*)d_in[19];
  const float* b_c1      = (const float*)d_in[20];
  const float* W_c2      = (const float*)d_in[21];
  const float* b_c2      = (const float*)d_in[22];
  const float* coral_w   = (const float*)d_in[23];
  const float* coral_b   = (const float*)d_in[24];

  dkvmn_kernel<<<dim3(BB), dim3(256), 0, stream>>>(
      q_data, r_data, q_embed, key_mem, init_mv,
      W_value, b_value, W_erase, b_erase, W_add, b_add,
      W_summary, b_summary, W_theta, b_theta, W_beta, b_beta,
      W_disc, b_disc, W_c1, b_c1, W_c2, b_c2, coral_w, coral_b,
      (float*)d_out);
}

// Round 2
// 4698.866 us; speedup vs baseline: 3.0185x; 3.0185x over previous
//
#include <hip/hip_runtime.h>
#include <math.h>

#define BB 128
#define SS 1024
#define MM 64
#define KDIM 128
#define VDIM 256
#define FDIM 128
#define QNUM 5000
#define QD 5001            // q ids 0..5000
#define RROWS (4 * QD)     // 20004 distinct (r,q) rows

__device__ __forceinline__ float sigmoidf_(float x) { return 1.0f / (1.0f + expf(-x)); }
__device__ __forceinline__ float softplusf_(float x) { return (x > 20.0f) ? x : log1pf(expf(x)); }

// ---------------- K1: E/A table over all (r,q): 20004 x 256 each ----------------
__global__ __launch_bounds__(256) void k_ea(
    const float* __restrict__ Wv, const float* __restrict__ bv,
    const float* __restrict__ We, const float* __restrict__ be,
    const float* __restrict__ Wa, const float* __restrict__ ba,
    float* __restrict__ Etab, float* __restrict__ Atab)
{
  const int tid = threadIdx.x;
  const int base = blockIdx.x * 16;
  __shared__ float sve[16][256];
#pragma unroll
  for (int j = 0; j < 16; ++j) {
    const int rr = base + j;
    float v = bv[tid];
    if (rr < RROWS) {
      const int q = rr % QD;
      const int r = rr / QD;
      if (q >= 1) {
        const float sc = (float)r * (1.0f / 3.0f);
        v += Wv[(size_t)(q - 1) * VDIM + tid] + sc * Wv[(size_t)(QNUM + q - 1) * VDIM + tid];
      }
    }
    sve[j][tid] = v;
  }
  __syncthreads();
  float ea[16], aa[16];
#pragma unroll
  for (int j = 0; j < 16; ++j) { ea[j] = 0.f; aa[j] = 0.f; }
#pragma unroll 4
  for (int i = 0; i < 256; ++i) {
    const float we = We[i * VDIM + tid];
    const float wa = Wa[i * VDIM + tid];
#pragma unroll
    for (int j = 0; j < 16; ++j) {
      ea[j] = fmaf(sve[j][i], we, ea[j]);
      aa[j] = fmaf(sve[j][i], wa, aa[j]);
    }
  }
  const float bev = be[tid], bav = ba[tid];
#pragma unroll
  for (int j = 0; j < 16; ++j) {
    const int rr = base + j;
    if (rr < RROWS) {
      Etab[(size_t)rr * VDIM + tid] = sigmoidf_(ea[j] + bev);
      Atab[(size_t)rr * VDIM + tid] = tanhf(aa[j] + bav);
    }
  }
}

// ---------------- K2: per-q tables: w (softmax), Sq (qe-part of summary), aq, betas ----------------
__global__ __launch_bounds__(256) void k_q(
    const float* __restrict__ q_embed, const float* __restrict__ key_mem,
    const float* __restrict__ W_summary, const float* __restrict__ b_summary,
    const float* __restrict__ W_disc,
    const float* __restrict__ W_beta, const float* __restrict__ b_beta,
    float* __restrict__ w_tab, float* __restrict__ Sq_tab,
    float* __restrict__ aq_tab, float* __restrict__ beta_tab)
{
  const int q = blockIdx.x;
  const int tid = threadIdx.x;
  const int wave = tid >> 6, l = tid & 63;
  __shared__ float qe[KDIM];
  __shared__ float slog[MM];
  if (tid < KDIM) qe[tid] = q_embed[(size_t)q * KDIM + tid];
  __syncthreads();
  // key logits: 4 threads per m
  {
    const int m = tid >> 2, j = tid & 3;
    const float* krow = key_mem + m * KDIM + j * 32;
    const float* qrow = qe + j * 32;
    float acc = 0.f;
#pragma unroll
    for (int k = 0; k < 32; ++k) {
      const int i = (k + tid) & 31;
      acc = fmaf(qrow[i], krow[i], acc);
    }
    acc += __shfl_xor(acc, 1);
    acc += __shfl_xor(acc, 2);
    if (j == 0) slog[m] = acc;
  }
  __syncthreads();
  if (wave == 0) {                 // softmax -> w_tab
    const float x = slog[l];
    float mx = x;
#pragma unroll
    for (int o = 32; o; o >>= 1) mx = fmaxf(mx, __shfl_xor(mx, o));
    const float e = expf(x - mx);
    float s = e;
#pragma unroll
    for (int o = 32; o; o >>= 1) s += __shfl_xor(s, o);
    w_tab[(size_t)q * MM + l] = e / s;
  } else if (wave == 1) {          // alpha qe-part
    float p = qe[l] * W_disc[KDIM + l] + qe[64 + l] * W_disc[KDIM + 64 + l];
#pragma unroll
    for (int o = 32; o; o >>= 1) p += __shfl_xor(p, o);
    if (l == 0) aq_tab[q] = p;
  } else if (wave == 2) {          // betas
    float p0 = qe[l] * W_beta[l * 3 + 0] + qe[64 + l] * W_beta[(64 + l) * 3 + 0];
    float p1 = qe[l] * W_beta[l * 3 + 1] + qe[64 + l] * W_beta[(64 + l) * 3 + 1];
    float p2 = qe[l] * W_beta[l * 3 + 2] + qe[64 + l] * W_beta[(64 + l) * 3 + 2];
#pragma unroll
    for (int o = 32; o; o >>= 1) {
      p0 += __shfl_xor(p0, o); p1 += __shfl_xor(p1, o); p2 += __shfl_xor(p2, o);
    }
    if (l == 0) {
      beta_tab[(size_t)q * 3 + 0] = p0 + b_beta[0];
      beta_tab[(size_t)q * 3 + 1] = p1 + b_beta[1];
      beta_tab[(size_t)q * 3 + 2] = p2 + b_beta[2];
    }
  }
  // Sq: qe-part of summary (rows 256..383 of W_summary), all 256 threads
  {
    const int f = tid >> 1, h = tid & 1;
    float acc = 0.f;
#pragma unroll 8
    for (int ii = 0; ii < 64; ++ii)
      acc = fmaf(qe[h * 64 + ii], W_summary[(size_t)(VDIM + h * 64 + ii) * FDIM + f], acc);
    acc += __shfl_xor(acc, 1);
    if (h == 0) Sq_tab[(size_t)q * FDIM + f] = acc + b_summary[f];
  }
}

// ---------------- K3: sequential scan ----------------
__global__ __launch_bounds__(256, 1) void k_scan(
    const int* __restrict__ q_data, const int* __restrict__ r_data,
    const float* __restrict__ init_mv,
    const float* __restrict__ W_summary,
    const float* __restrict__ W_theta, const float* __restrict__ b_theta,
    const float* __restrict__ W_disc, const float* __restrict__ b_disc,
    const float* __restrict__ W_c1, const float* __restrict__ b_c1,
    const float* __restrict__ W_c2, const float* __restrict__ b_c2,
    const float* __restrict__ coral_w, const float* __restrict__ coral_b,
    const float* __restrict__ Etab, const float* __restrict__ Atab,
    const float* __restrict__ w_tab, const float* __restrict__ Sq_tab,
    const float* __restrict__ aq_tab, const float* __restrict__ beta_tab,
    float* __restrict__ out)
{
  const int b = blockIdx.x;
  const int tid = threadIdx.x;
  const int wave = tid >> 6, l = tid & 63;
  const int f = tid >> 1, h = tid & 1;

  __shared__ int   s_qt[SS];
  __shared__ int   s_rt[SS];
  __shared__ float s_w[2][MM];
  __shared__ float s_Sq[2][FDIM];
  __shared__ float s_misc[2][4];     // [0]=aq, [1..3]=betas
  __shared__ float s_read[VDIM];
  __shared__ float s_summary[FDIM];
  __shared__ float s_feat[8];

  for (int i = tid; i < SS; i += 256) {
    s_qt[i] = q_data[(size_t)b * SS + i];
    s_rt[i] = r_data[(size_t)b * SS + i];
  }

  // register-resident read-part of W_summary: thread (f,h) holds column f, rows h*128..h*128+127
  float wreg[128];
#pragma unroll
  for (int i = 0; i < 128; ++i)
    wreg[i] = W_summary[(size_t)((h << 7) + i) * FDIM + f];

  // Mv state: thread v=tid owns Mv[m][v]
  float mv[MM];
#pragma unroll
  for (int m = 0; m < MM; ++m) mv[m] = init_mv[m * VDIM + tid];

  // head weights
  float tw0 = 0.f, tw1 = 0.f, tb = 0.f, dw0 = 0.f, dw1 = 0.f, db = 0.f;
  if (wave == 0) { tw0 = W_theta[l]; tw1 = W_theta[l + 64]; tb = b_theta[0]; }
  if (wave == 1) { dw0 = W_disc[l]; dw1 = W_disc[l + 64]; db = b_disc[0]; }

  // CORAL register weights (wave 0): lane l computes h1[l]; pair (jj,hh2) computes h2[jj]
  const int jj = l >> 1, hh2 = l & 1;
  float wc1reg[5]; float wc2reg[32];
  float bc1reg = 0.f, bc2reg = 0.f, cwreg = 0.f;
  float cb0 = 0.f, cb1 = 0.f, cb2 = 0.f;
  if (wave == 0) {
#pragma unroll
    for (int i = 0; i < 5; ++i) wc1reg[i] = W_c1[i * 64 + l];
#pragma unroll
    for (int i = 0; i < 32; ++i) wc2reg[i] = W_c2[(hh2 * 32 + i) * 32 + jj];
    bc1reg = b_c1[l];
    bc2reg = b_c2[jj];
    cwreg = coral_w[jj];
    if (l == 0) { cb0 = coral_b[0]; cb1 = coral_b[1]; cb2 = coral_b[2]; }
  } else {
#pragma unroll
    for (int i = 0; i < 5; ++i) wc1reg[i] = 0.f;
#pragma unroll
    for (int i = 0; i < 32; ++i) wc2reg[i] = 0.f;
  }

  float* out_theta = out;
  float* out_beta  = out + (size_t)BB * SS;
  float* out_alpha = out + (size_t)BB * SS * 4;
  float* out_probs = out + (size_t)BB * SS * 5;
  float* out_logit = out + (size_t)BB * SS * 9;

  __syncthreads();

  // stage t=0 into buffer 0
  {
    const int q0 = s_qt[0];
    if (wave == 3) {
      s_w[0][l] = w_tab[(size_t)q0 * MM + l];
      s_Sq[0][l] = Sq_tab[(size_t)q0 * FDIM + l];
      s_Sq[0][64 + l] = Sq_tab[(size_t)q0 * FDIM + 64 + l];
      if (l == 4) s_misc[0][0] = aq_tab[q0];
      if (l < 3) s_misc[0][1 + l] = beta_tab[(size_t)q0 * 3 + l];
    }
  }
  float e_cur, a_cur;
  {
    const size_t row0 = (size_t)s_rt[0] * QD + s_qt[0];
    e_cur = Etab[row0 * VDIM + tid];
    a_cur = Atab[row0 * VDIM + tid];
  }
  __syncthreads();

  for (int t = 0; t < SS; ++t) {
    const int cur = t & 1, nxt = cur ^ 1;
    const int tn = (t + 1 < SS) ? (t + 1) : t;

    // ---- prefetch step t+1 (state-independent) ----
    const int qn = s_qt[tn], rn = s_rt[tn];
    const size_t rowN = (size_t)rn * QD + qn;
    const float e_nx = Etab[rowN * VDIM + tid];
    const float a_nx = Atab[rowN * VDIM + tid];
    if (wave == 3) {
      s_w[nxt][l] = w_tab[(size_t)qn * MM + l];
      s_Sq[nxt][l] = Sq_tab[(size_t)qn * FDIM + l];
      s_Sq[nxt][64 + l] = Sq_tab[(size_t)qn * FDIM + 64 + l];
      if (l == 4) s_misc[nxt][0] = aq_tab[qn];
      if (l < 3) s_misc[nxt][1 + l] = beta_tab[(size_t)qn * 3 + l];
    }

    // ---- fused read + Mv update (thread v=tid) ----
    {
      const float4* w4 = (const float4*)s_w[cur];
      float rd = 0.f;
#pragma unroll
      for (int k = 0; k < 16; ++k) {
        const float4 ww = w4[k];
        float t0;
        rd = fmaf(ww.x, mv[4 * k + 0], rd);
        t0 = fmaf(-e_cur, mv[4 * k + 0], a_cur); mv[4 * k + 0] = fmaf(ww.x, t0, mv[4 * k + 0]);
        rd = fmaf(ww.y, mv[4 * k + 1], rd);
        t0 = fmaf(-e_cur, mv[4 * k + 1], a_cur); mv[4 * k + 1] = fmaf(ww.y, t0, mv[4 * k + 1]);
        rd = fmaf(ww.z, mv[4 * k + 2], rd);
        t0 = fmaf(-e_cur, mv[4 * k + 2], a_cur); mv[4 * k + 2] = fmaf(ww.z, t0, mv[4 * k + 2]);
        rd = fmaf(ww.w, mv[4 * k + 3], rd);
        t0 = fmaf(-e_cur, mv[4 * k + 3], a_cur); mv[4 * k + 3] = fmaf(ww.w, t0, mv[4 * k + 3]);
      }
      s_read[tid] = rd;
    }
    __syncthreads();  // B1: s_read ready

    // ---- summary: thread (f,h), register weights, float4 broadcast reads ----
    {
      const float4* r4 = (const float4*)s_read;
      float acc = (h == 0) ? s_Sq[cur][f] : 0.f;
#pragma unroll
      for (int k = 0; k < 32; ++k) {
        const float4 rr = r4[(h << 5) + k];
        acc = fmaf(rr.x, wreg[4 * k + 0], acc);
        acc = fmaf(rr.y, wreg[4 * k + 1], acc);
        acc = fmaf(rr.z, wreg[4 * k + 2], acc);
        acc = fmaf(rr.w, wreg[4 * k + 3], acc);
      }
      acc += __shfl_xor(acc, 1);
      if (h == 0) s_summary[f] = tanhf(acc);
    }
    __syncthreads();  // B2: s_summary ready

    // ---- heads ----
    if (wave == 0) {
      float a = fmaf(s_summary[l], tw0, s_summary[l + 64] * tw1);
#pragma unroll
      for (int o = 32; o; o >>= 1) a += __shfl_xor(a, o);
      if (l == 0) s_feat[0] = (a + tb) * 3.0f;
    } else if (wave == 1) {
      float a = fmaf(s_summary[l], dw0, s_summary[l + 64] * dw1);
#pragma unroll
      for (int o = 32; o; o >>= 1) a += __shfl_xor(a, o);
      if (l == 0) s_feat[1] = softplusf_(a + s_misc[cur][0] + db);
    } else if (wave == 2) {
      if (l < 3) s_feat[2 + l] = s_misc[cur][1 + l];
    }
    __syncthreads();  // B3: s_feat ready

    // ---- CORAL MLP in wave 0 (registers + shuffles) ----
    if (wave == 0) {
      float h1 = bc1reg;
#pragma unroll
      for (int i = 0; i < 5; ++i) h1 = fmaf(s_feat[i], wc1reg[i], h1);
      h1 = fmaxf(h1, 0.f);
      float hacc = hh2 ? 0.f : bc2reg;
#pragma unroll
      for (int ii = 0; ii < 32; ++ii)
        hacc = fmaf(__shfl(h1, (hh2 << 5) + ii), wc2reg[ii], hacc);
      hacc += __shfl_xor(hacc, 1);           // pair sum -> full h2[jj] in both lanes
      const float h2 = fmaxf(hacc, 0.f);
      float p = h2 * cwreg * 0.5f;           // each j counted twice across the wave
#pragma unroll
      for (int o = 32; o; o >>= 1) p += __shfl_xor(p, o);
      if (l == 0) {
        const float z = p;
        const float l0 = z + cb0, l1 = z + cb1, l2 = z + cb2;
        const float s0 = sigmoidf_(l0), s1 = sigmoidf_(l1), s2 = sigmoidf_(l2);
        const float c0 = s0, c1 = s0 * s1, c2 = s0 * s1 * s2;
        const size_t bt = (size_t)b * SS + t;
        out_theta[bt] = s_feat[0];
        out_alpha[bt] = s_feat[1];
        out_beta[bt * 3 + 0] = s_feat[2];
        out_beta[bt * 3 + 1] = s_feat[3];
        out_beta[bt * 3 + 2] = s_feat[4];
        out_logit[bt * 3 + 0] = l0;
        out_logit[bt * 3 + 1] = l1;
        out_logit[bt * 3 + 2] = l2;
        out_probs[bt * 4 + 0] = 1.f - c0;
        out_probs[bt * 4 + 1] = c0 - c1;
        out_probs[bt * 4 + 2] = c1 - c2;
        out_probs[bt * 4 + 3] = c2;
      }
    }

    e_cur = e_nx; a_cur = a_nx;
    __syncthreads();  // B4: staging visible; s_read/s_summary/s_feat safe to overwrite
  }
}

extern "C" void kernel_launch(void* const* d_in, const int* in_sizes, int n_in,
                              void* d_out, int out_size, void* d_ws, size_t ws_size,
                              hipStream_t stream) {
  const int*   q_data    = (const int*)d_in[0];
  const int*   r_data    = (const int*)d_in[1];
  const float* q_embed   = (const float*)d_in[2];
  const float* key_mem   = (const float*)d_in[3];
  const float* init_mv   = (const float*)d_in[4];
  const float* W_value   = (const float*)d_in[5];
  const float* b_value   = (const float*)d_in[6];
  const float* W_erase   = (const float*)d_in[7];
  const float* b_erase   = (const float*)d_in[8];
  const float* W_add     = (const float*)d_in[9];
  const float* b_add     = (const float*)d_in[10];
  const float* W_summary = (const float*)d_in[11];
  const float* b_summary = (const float*)d_in[12];
  const float* W_theta   = (const float*)d_in[13];
  const float* b_theta   = (const float*)d_in[14];
  const float* W_beta    = (const float*)d_in[15];
  const float* b_beta    = (const float*)d_in[16];
  const float* W_disc    = (const float*)d_in[17];
  const float* b_disc    = (const float*)d_in[18];
  const float* W_c1      = (const float*)d_in[19];
  const float* b_c1      = (const float*)d_in[20];
  const float* W_c2      = (const float*)d_in[21];
  const float* b_c2      = (const float*)d_in[22];
  const float* coral_w   = (const float*)d_in[23];
  const float* coral_b   = (const float*)d_in[24];

  // workspace carve (floats)
  float* ws = (float*)d_ws;
  float* Etab    = ws;                                   // 20004*256
  float* Atab    = Etab + (size_t)RROWS * VDIM;          // 20004*256
  float* w_tab   = Atab + (size_t)RROWS * VDIM;          // 5001*64
  float* Sq_tab  = w_tab + (size_t)QD * MM;              // 5001*128
  float* aq_tab  = Sq_tab + (size_t)QD * FDIM;           // 5001
  float* beta_tab= aq_tab + QD;                          // 5001*3

  k_ea<<<dim3((RROWS + 15) / 16), dim3(256), 0, stream>>>(
      W_value, b_value, W_erase, b_erase, W_add, b_add, Etab, Atab);

  k_q<<<dim3(QD), dim3(256), 0, stream>>>(
      q_embed, key_mem, W_summary, b_summary, W_disc, W_beta, b_beta,
      w_tab, Sq_tab, aq_tab, beta_tab);

  k_scan<<<dim3(BB), dim3(256), 0, stream>>>(
      q_data, r_data, init_mv, W_summary, W_theta, b_theta, W_disc, b_disc,
      W_c1, b_c1, W_c2, b_c2, coral_w, coral_b,
      Etab, Atab, w_tab, Sq_tab, aq_tab, beta_tab, (float*)d_out);
}

// Round 3
// 1034.489 us; speedup vs baseline: 13.7108x; 4.5422x over previous
//
#include <hip/hip_runtime.h>
#include <math.h>

#define BB 128
#define SS 1024
#define MM 64
#define KDIM 128
#define VDIM 256
#define FDIM 128
#define QNUM 5000
#define QD 5001            // q ids 0..5000
#define RROWS (4 * QD)     // 20004 distinct (r,q) rows

typedef _Float16 half2_t __attribute__((ext_vector_type(2)));
union U4 { uint4 u; half2_t h[4]; };

#if defined(__has_builtin)
#if __has_builtin(__builtin_amdgcn_fdot2)
#define HAVE_FDOT2 1
#endif
#endif

__device__ __forceinline__ float dot2_(half2_t a, half2_t b, float c) {
#ifdef HAVE_FDOT2
  return __builtin_amdgcn_fdot2(a, b, c, false);
#else
  return c + (float)a[0] * (float)b[0] + (float)a[1] * (float)b[1];
#endif
}

__device__ __forceinline__ float sigmoidf_(float x) { return 1.0f / (1.0f + expf(-x)); }
__device__ __forceinline__ float softplusf_(float x) { return (x > 20.0f) ? x : log1pf(expf(x)); }

// ---------------- K0: W_summary read-part -> f16, [f][k] layout ----------------
__global__ __launch_bounds__(256) void k_prep(const float* __restrict__ W_summary,
                                              _Float16* __restrict__ Wh)
{
  const int e = blockIdx.x * 256 + threadIdx.x;   // 0..32767
  const int f = e >> 8, k = e & 255;
  Wh[(size_t)f * 256 + k] = (_Float16)W_summary[(size_t)k * FDIM + f];
}

// ---------------- K1: E/A table over all (r,q): 20004 x 256 each ----------------
__global__ __launch_bounds__(256) void k_ea(
    const float* __restrict__ Wv, const float* __restrict__ bv,
    const float* __restrict__ We, const float* __restrict__ be,
    const float* __restrict__ Wa, const float* __restrict__ ba,
    float* __restrict__ Etab, float* __restrict__ Atab)
{
  const int tid = threadIdx.x;
  const int base = blockIdx.x * 16;
  __shared__ float sve[16][256];
#pragma unroll
  for (int j = 0; j < 16; ++j) {
    const int rr = base + j;
    float v = bv[tid];
    if (rr < RROWS) {
      const int q = rr % QD;
      const int r = rr / QD;
      if (q >= 1) {
        const float sc = (float)r * (1.0f / 3.0f);
        v += Wv[(size_t)(q - 1) * VDIM + tid] + sc * Wv[(size_t)(QNUM + q - 1) * VDIM + tid];
      }
    }
    sve[j][tid] = v;
  }
  __syncthreads();
  float ea[16], aa[16];
#pragma unroll
  for (int j = 0; j < 16; ++j) { ea[j] = 0.f; aa[j] = 0.f; }
#pragma unroll 4
  for (int i = 0; i < 256; ++i) {
    const float we = We[i * VDIM + tid];
    const float wa = Wa[i * VDIM + tid];
#pragma unroll
    for (int j = 0; j < 16; ++j) {
      ea[j] = fmaf(sve[j][i], we, ea[j]);
      aa[j] = fmaf(sve[j][i], wa, aa[j]);
    }
  }
  const float bev = be[tid], bav = ba[tid];
#pragma unroll
  for (int j = 0; j < 16; ++j) {
    const int rr = base + j;
    if (rr < RROWS) {
      Etab[(size_t)rr * VDIM + tid] = sigmoidf_(ea[j] + bev);
      Atab[(size_t)rr * VDIM + tid] = tanhf(aa[j] + bav);
    }
  }
}

// ---------------- K2: per-q tables: w (softmax), Sq, aq, betas ----------------
__global__ __launch_bounds__(256) void k_q(
    const float* __restrict__ q_embed, const float* __restrict__ key_mem,
    const float* __restrict__ W_summary, const float* __restrict__ b_summary,
    const float* __restrict__ W_disc,
    const float* __restrict__ W_beta, const float* __restrict__ b_beta,
    float* __restrict__ w_tab, float* __restrict__ Sq_tab,
    float* __restrict__ aq_tab, float* __restrict__ beta_tab)
{
  const int q = blockIdx.x;
  const int tid = threadIdx.x;
  const int wave = tid >> 6, l = tid & 63;
  __shared__ float qe[KDIM];
  __shared__ float slog[MM];
  if (tid < KDIM) qe[tid] = q_embed[(size_t)q * KDIM + tid];
  __syncthreads();
  {
    const int m = tid >> 2, j = tid & 3;
    const float* krow = key_mem + m * KDIM + j * 32;
    const float* qrow = qe + j * 32;
    float acc = 0.f;
#pragma unroll
    for (int k = 0; k < 32; ++k) {
      const int i = (k + tid) & 31;
      acc = fmaf(qrow[i], krow[i], acc);
    }
    acc += __shfl_xor(acc, 1);
    acc += __shfl_xor(acc, 2);
    if (j == 0) slog[m] = acc;
  }
  __syncthreads();
  if (wave == 0) {
    const float x = slog[l];
    float mx = x;
#pragma unroll
    for (int o = 32; o; o >>= 1) mx = fmaxf(mx, __shfl_xor(mx, o));
    const float e = expf(x - mx);
    float s = e;
#pragma unroll
    for (int o = 32; o; o >>= 1) s += __shfl_xor(s, o);
    w_tab[(size_t)q * MM + l] = e / s;
  } else if (wave == 1) {
    float p = qe[l] * W_disc[KDIM + l] + qe[64 + l] * W_disc[KDIM + 64 + l];
#pragma unroll
    for (int o = 32; o; o >>= 1) p += __shfl_xor(p, o);
    if (l == 0) aq_tab[q] = p;
  } else if (wave == 2) {
    float p0 = qe[l] * W_beta[l * 3 + 0] + qe[64 + l] * W_beta[(64 + l) * 3 + 0];
    float p1 = qe[l] * W_beta[l * 3 + 1] + qe[64 + l] * W_beta[(64 + l) * 3 + 1];
    float p2 = qe[l] * W_beta[l * 3 + 2] + qe[64 + l] * W_beta[(64 + l) * 3 + 2];
#pragma unroll
    for (int o = 32; o; o >>= 1) {
      p0 += __shfl_xor(p0, o); p1 += __shfl_xor(p1, o); p2 += __shfl_xor(p2, o);
    }
    if (l == 0) {
      beta_tab[(size_t)q * 3 + 0] = p0 + b_beta[0];
      beta_tab[(size_t)q * 3 + 1] = p1 + b_beta[1];
      beta_tab[(size_t)q * 3 + 2] = p2 + b_beta[2];
    }
  }
  {
    const int f = tid >> 1, h = tid & 1;
    float acc = 0.f;
#pragma unroll 8
    for (int ii = 0; ii < 64; ++ii)
      acc = fmaf(qe[h * 64 + ii], W_summary[(size_t)(VDIM + h * 64 + ii) * FDIM + f], acc);
    acc += __shfl_xor(acc, 1);
    if (h == 0) Sq_tab[(size_t)q * FDIM + f] = acc + b_summary[f];
  }
}

// ---------------- K3: recurrence only (one wave per (b, v-chunk)) ----------------
__global__ __launch_bounds__(64) void k_rec(
    const int* __restrict__ q_data, const int* __restrict__ r_data,
    const float* __restrict__ init_mv,
    const float* __restrict__ Etab, const float* __restrict__ Atab,
    const float* __restrict__ w_tab,
    _Float16* __restrict__ Rd)
{
  const int lane = threadIdx.x;
  const int b = blockIdx.x >> 2;
  const int c = blockIdx.x & 3;
  const int v = c * 64 + lane;

  __shared__ int s_qt[SS], s_rt[SS];
  __shared__ __align__(16) float s_w[8][MM];

  for (int i = lane; i < SS; i += 64) {
    s_qt[i] = q_data[b * SS + i];
    s_rt[i] = r_data[b * SS + i];
  }
  __syncthreads();

  float mv[MM];
#pragma unroll
  for (int m = 0; m < MM; ++m) mv[m] = init_mv[m * VDIM + v];

  float eD[4], aD[4];
#pragma unroll
  for (int j = 0; j < 4; ++j) {
    const int q = s_qt[j], r = s_rt[j];
    const size_t row = ((size_t)(r * QD + q)) * VDIM + v;
    eD[j] = Etab[row]; aD[j] = Atab[row];
    s_w[j][lane] = w_tab[(size_t)q * MM + lane];
  }
  __syncthreads();

  _Float16* outp = Rd + ((size_t)b * SS) * VDIM + v;

  for (int g = 0; g < SS / 4; ++g) {
    const int t = g * 4;
    const int cb = (g & 1) * 4, nb = ((g + 1) & 1) * 4;
    // prefetch group g+1 (state-independent)
    float eN[4], aN[4];
#pragma unroll
    for (int j = 0; j < 4; ++j) {
      int tp = t + 4 + j; if (tp >= SS) tp = SS - 1;
      const int q = s_qt[tp], r = s_rt[tp];
      const size_t row = ((size_t)(r * QD + q)) * VDIM + v;
      eN[j] = Etab[row]; aN[j] = Atab[row];
      s_w[nb + j][lane] = w_tab[(size_t)q * MM + lane];
    }
    // process 4 steps
#pragma unroll
    for (int j = 0; j < 4; ++j) {
      const float4* w4 = (const float4*)s_w[cb + j];
      const float e = eD[j], a = aD[j];
      float r0 = 0.f, r1 = 0.f, r2 = 0.f, r3 = 0.f;
#pragma unroll
      for (int k = 0; k < 16; ++k) {
        const float4 ww = w4[k];
        float t0;
        r0 = fmaf(ww.x, mv[4 * k + 0], r0);
        t0 = fmaf(-e, mv[4 * k + 0], a); mv[4 * k + 0] = fmaf(ww.x, t0, mv[4 * k + 0]);
        r1 = fmaf(ww.y, mv[4 * k + 1], r1);
        t0 = fmaf(-e, mv[4 * k + 1], a); mv[4 * k + 1] = fmaf(ww.y, t0, mv[4 * k + 1]);
        r2 = fmaf(ww.z, mv[4 * k + 2], r2);
        t0 = fmaf(-e, mv[4 * k + 2], a); mv[4 * k + 2] = fmaf(ww.z, t0, mv[4 * k + 2]);
        r3 = fmaf(ww.w, mv[4 * k + 3], r3);
        t0 = fmaf(-e, mv[4 * k + 3], a); mv[4 * k + 3] = fmaf(ww.w, t0, mv[4 * k + 3]);
      }
      outp[(size_t)(t + j) * VDIM] = (_Float16)((r0 + r1) + (r2 + r3));
    }
#pragma unroll
    for (int j = 0; j < 4; ++j) { eD[j] = eN[j]; aD[j] = aN[j]; }
    __syncthreads();  // order w-ring write(g+1) before read(g+1); single wave -> cheap
  }
}

// ---------------- K4: parallel summary GEMM + heads + CORAL over all (b,t) ----------------
__global__ __launch_bounds__(256) void k_head(
    const int* __restrict__ q_data,
    const _Float16* __restrict__ Rd, const _Float16* __restrict__ Wh,
    const float* __restrict__ Sq_tab, const float* __restrict__ aq_tab,
    const float* __restrict__ beta_tab,
    const float* __restrict__ W_theta, const float* __restrict__ b_theta,
    const float* __restrict__ W_disc, const float* __restrict__ b_disc,
    const float* __restrict__ W_c1, const float* __restrict__ b_c1,
    const float* __restrict__ W_c2, const float* __restrict__ b_c2,
    const float* __restrict__ coral_w, const float* __restrict__ coral_b,
    float* __restrict__ out)
{
  const int tid = threadIdx.x;
  const int w = tid >> 6, l = tid & 63;
  const int rowbase = blockIdx.x * 64;           // 64 rows (same b: 64 | 1024)
  const int b = rowbase >> 10;
  const int t0 = rowbase & (SS - 1);

  __shared__ __align__(16) _Float16 s_A[64 * 256];   // 32 KB
  __shared__ __align__(16) _Float16 s_sum[64 * 128]; // 16 KB
  __shared__ int   s_q[64];
  __shared__ float s_aq[64];
  __shared__ float s_be[64][3];

  // stage A (f16 read rows)
  {
    const uint4* src = (const uint4*)(Rd + (size_t)rowbase * VDIM);
    uint4* dst = (uint4*)s_A;
    for (int i = tid; i < (64 * 256 * 2) / 16; i += 256) dst[i] = src[i];
  }
  if (tid < 64) {
    const int q = q_data[b * SS + t0 + tid];
    s_q[tid] = q;
    s_aq[tid] = aq_tab[q];
    s_be[tid][0] = beta_tab[(size_t)q * 3 + 0];
    s_be[tid][1] = beta_tab[(size_t)q * 3 + 1];
    s_be[tid][2] = beta_tab[(size_t)q * 3 + 2];
  }

  // W regs: lane (fp,g) covers f0=fbase+2fp, f1=f0+1; k-half g*128
  const int fp = l >> 1, g = l & 1;
  const int fbase = (w & 1) * 64;
  const int f0 = fbase + 2 * fp, f1 = f0 + 1;
  U4 wr0[16], wr1[16];
  {
    const uint4* p0 = (const uint4*)(Wh + (size_t)f0 * 256 + g * 128);
    const uint4* p1 = (const uint4*)(Wh + (size_t)f1 * 256 + g * 128);
#pragma unroll
    for (int i = 0; i < 16; ++i) { wr0[i].u = p0[i]; wr1[i].u = p1[i]; }
  }
  __syncthreads();

  // GEMM: waves {0,1} even rows, {2,3} odd rows; f split by (w&1)
  for (int rp = 0; rp < 32; ++rp) {
    const int r = 2 * rp + (w >> 1);
    const uint4* a4 = (const uint4*)(s_A + r * 256 + g * 128);
    float a0 = 0.f, a1 = 0.f, c0 = 0.f, c1 = 0.f;
#pragma unroll
    for (int i = 0; i < 16; i += 2) {
      U4 x; x.u = a4[i];
      U4 y; y.u = a4[i + 1];
#pragma unroll
      for (int j = 0; j < 4; ++j) {
        a0 = dot2_(x.h[j], wr0[i].h[j], a0);
        a1 = dot2_(x.h[j], wr1[i].h[j], a1);
        c0 = dot2_(y.h[j], wr0[i + 1].h[j], c0);
        c1 = dot2_(y.h[j], wr1[i + 1].h[j], c1);
      }
    }
    float f0acc = a0 + c0, f1acc = a1 + c1;
    f0acc += __shfl_xor(f0acc, 1);
    f1acc += __shfl_xor(f1acc, 1);
    if (g == 0) {
      const float2 sq = *(const float2*)(Sq_tab + (size_t)s_q[r] * FDIM + f0);
      s_sum[r * 128 + f0] = (_Float16)tanhf(f0acc + sq.x);
      s_sum[r * 128 + f1] = (_Float16)tanhf(f1acc + sq.y);
    }
  }
  __syncthreads();

  // heads + CORAL: wave w handles rows w*16..w*16+15
  const float tw0 = W_theta[l], tw1 = W_theta[64 + l], tb = b_theta[0];
  const float dw0 = W_disc[l], dw1 = W_disc[64 + l], db = b_disc[0];
  float wc1reg[5];
#pragma unroll
  for (int i = 0; i < 5; ++i) wc1reg[i] = W_c1[i * 64 + l];
  const float bc1 = b_c1[l];
  const int jj = l >> 1, hh2 = l & 1;
  float wc2reg[32];
#pragma unroll
  for (int i = 0; i < 32; ++i) wc2reg[i] = W_c2[(hh2 * 32 + i) * 32 + jj];
  const float bc2 = b_c2[jj];
  const float cw = coral_w[jj];
  const float cb0 = coral_b[0], cb1 = coral_b[1], cb2 = coral_b[2];

  float* out_theta = out;
  float* out_beta  = out + (size_t)BB * SS;
  float* out_alpha = out + (size_t)BB * SS * 4;
  float* out_probs = out + (size_t)BB * SS * 5;
  float* out_logit = out + (size_t)BB * SS * 9;

  for (int rr = 0; rr < 16; ++rr) {
    const int r = w * 16 + rr;
    const float su0 = (float)s_sum[r * 128 + l];
    const float su1 = (float)s_sum[r * 128 + 64 + l];
    float at = su0 * tw0 + su1 * tw1;
    float ad = su0 * dw0 + su1 * dw1;
#pragma unroll
    for (int o = 32; o; o >>= 1) { at += __shfl_xor(at, o); ad += __shfl_xor(ad, o); }
    const float theta = (at + tb) * 3.0f;
    const float alpha = softplusf_(ad + s_aq[r] + db);
    const float be0 = s_be[r][0], be1 = s_be[r][1], be2 = s_be[r][2];
    float h1 = bc1;
    h1 = fmaf(theta, wc1reg[0], h1);
    h1 = fmaf(alpha, wc1reg[1], h1);
    h1 = fmaf(be0, wc1reg[2], h1);
    h1 = fmaf(be1, wc1reg[3], h1);
    h1 = fmaf(be2, wc1reg[4], h1);
    h1 = fmaxf(h1, 0.f);
    float hacc = hh2 ? 0.f : bc2;
#pragma unroll
    for (int i = 0; i < 32; ++i)
      hacc = fmaf(__shfl(h1, hh2 * 32 + i), wc2reg[i], hacc);
    hacc += __shfl_xor(hacc, 1);
    const float h2 = fmaxf(hacc, 0.f);
    float p = h2 * cw * 0.5f;
#pragma unroll
    for (int o = 32; o; o >>= 1) p += __shfl_xor(p, o);
    if (l == 0) {
      const float z = p;
      const float l0 = z + cb0, l1 = z + cb1, l2 = z + cb2;
      const float s0 = sigmoidf_(l0), s1 = sigmoidf_(l1), s2 = sigmoidf_(l2);
      const float q0 = s0, q1 = s0 * s1, q2 = s0 * s1 * s2;
      const size_t bt = (size_t)rowbase + r;   // == b*SS + t
      out_theta[bt] = theta;
      out_alpha[bt] = alpha;
      out_beta[bt * 3 + 0] = be0;
      out_beta[bt * 3 + 1] = be1;
      out_beta[bt * 3 + 2] = be2;
      out_logit[bt * 3 + 0] = l0;
      out_logit[bt * 3 + 1] = l1;
      out_logit[bt * 3 + 2] = l2;
      out_probs[bt * 4 + 0] = 1.f - q0;
      out_probs[bt * 4 + 1] = q0 - q1;
      out_probs[bt * 4 + 2] = q1 - q2;
      out_probs[bt * 4 + 3] = q2;
    }
  }
}

extern "C" void kernel_launch(void* const* d_in, const int* in_sizes, int n_in,
                              void* d_out, int out_size, void* d_ws, size_t ws_size,
                              hipStream_t stream) {
  const int*   q_data    = (const int*)d_in[0];
  const int*   r_data    = (const int*)d_in[1];
  const float* q_embed   = (const float*)d_in[2];
  const float* key_mem   = (const float*)d_in[3];
  const float* init_mv   = (const float*)d_in[4];
  const float* W_value   = (const float*)d_in[5];
  const float* b_value   = (const float*)d_in[6];
  const float* W_erase   = (const float*)d_in[7];
  const float* b_erase   = (const float*)d_in[8];
  const float* W_add     = (const float*)d_in[9];
  const float* b_add     = (const float*)d_in[10];
  const float* W_summary = (const float*)d_in[11];
  const float* b_summary = (const float*)d_in[12];
  const float* W_theta   = (const float*)d_in[13];
  const float* b_theta   = (const float*)d_in[14];
  const float* W_disc    = (const float*)d_in[15];
  const float* b_disc    = (const float*)d_in[16];
  const float* W_c1      = (const float*)d_in[19];
  const float* b_c1      = (const float*)d_in[20];
  const float* W_c2      = (const float*)d_in[21];
  const float* b_c2      = (const float*)d_in[22];
  const float* coral_w   = (const float*)d_in[23];
  const float* coral_b   = (const float*)d_in[24];
  const float* W_beta    = (const float*)d_in[15];
  const float* b_beta    = (const float*)d_in[16];
  const float* W_disc2   = (const float*)d_in[17];
  const float* b_disc2   = (const float*)d_in[18];

  // NOTE input order per setup_inputs: 15=W_beta,16=b_beta,17=W_disc,18=b_disc
  W_beta  = (const float*)d_in[15];
  b_beta  = (const float*)d_in[16];
  W_disc  = (const float*)d_in[17];
  b_disc  = (const float*)d_in[18];
  (void)W_disc2; (void)b_disc2;

  float* ws = (float*)d_ws;
  size_t off = 0;
  float* Etab     = ws + off; off += (size_t)RROWS * VDIM;   // 5,121,024
  float* Atab     = ws + off; off += (size_t)RROWS * VDIM;
  float* w_tab    = ws + off; off += (size_t)QD * MM;        // 320,064
  float* Sq_tab   = ws + off; off += (size_t)QD * FDIM;      // 640,128
  float* aq_tab   = ws + off; off += 5120;
  float* beta_tab = ws + off; off += 15104;
  _Float16* Wh = (_Float16*)(ws + off); off += (VDIM * FDIM) / 2;   // 32768 f16
  _Float16* Rd = (_Float16*)(ws + off);                             // 131072*256 f16

  k_prep<<<dim3(128), dim3(256), 0, stream>>>(W_summary, Wh);

  k_ea<<<dim3((RROWS + 15) / 16), dim3(256), 0, stream>>>(
      W_value, b_value, W_erase, b_erase, W_add, b_add, Etab, Atab);

  k_q<<<dim3(QD), dim3(256), 0, stream>>>(
      q_embed, key_mem, W_summary, b_summary, W_disc, W_beta, b_beta,
      w_tab, Sq_tab, aq_tab, beta_tab);

  k_rec<<<dim3(BB * 4), dim3(64), 0, stream>>>(
      q_data, r_data, init_mv, Etab, Atab, w_tab, Rd);

  k_head<<<dim3((BB * SS) / 64), dim3(256), 0, stream>>>(
      q_data, Rd, Wh, Sq_tab, aq_tab, beta_tab,
      W_theta, b_theta, W_disc, b_disc,
      W_c1, b_c1, W_c2, b_c2, coral_w, coral_b, (float*)d_out);
}